// Round 7
// baseline (329.151 us; speedup 1.0000x reference)
//
#include <hip/hip_runtime.h>
#include <hip/hip_bf16.h>
#include <math.h>

#define N_NODES 100000
#define NE      3200000
#define TWO_NE  (2 * NE)
#define TWO_N   (2 * N_NODES)
#define H       32
#define DAMPING 0.1f
#define LN_EPS  1e-5f

#define NBUCK    782           // ceil(2N / 256) coarse dst buckets (256 rows each)
#define CAP_PAD  11776         // bucket region: 8192 mean + 90 sigma counts + 16-pads + margin
#define CAP_STG  8960          // LDS staging cap (counts only; mean 8192 + 8.5 sigma)
#define EPB      8192          // edges per scatter block
#define NBLK_A   ((TWO_NE + EPB - 1) / EPB)   // 782
#define ZROW     TWO_N         // dedicated all-zero xh row used for padding

// ---------------------------------------------------------------------------
// Kernel 0: init per-bucket cursors to fixed-capacity bases + zero the pad row
// of xh. (Re-done every launch: harness re-poisons ws with 0xAA.)
// ---------------------------------------------------------------------------
__global__ __launch_bounds__(256) void init_kernel(
    int* __restrict__ gcur, unsigned int* __restrict__ xhz)
{
    int i = blockIdx.x * 256 + threadIdx.x;
    if (i < NBUCK) gcur[i] = i * CAP_PAD;
    if (i < 16)    xhz[i] = 0;             // xh row ZROW (16 x bf16x2 = 64 B)
}

// ---------------------------------------------------------------------------
// Kernel 1 (pass A): two-level bucket append, register-held edges. Per edge:
// LDS hist atomic -> one global claim per (block,bucket) -> LDS rank atomic +
// direct 4B write. Runs are L2-combined within the block's XCD.
// rec = (dst' & 255) << 18 | src'   (src' < 2^18)
// ---------------------------------------------------------------------------
__global__ __launch_bounds__(256) void bucket_scatter_kernel(
    const int* __restrict__ ep, const int* __restrict__ en,
    int* __restrict__ gcur, unsigned int* __restrict__ buf)
{
    __shared__ int hist[NBUCK];
    __shared__ int lcur[NBUCK];
    __shared__ int claim[NBUCK];

    int t = threadIdx.x;
    for (int i = t; i < NBUCK; i += 256) { hist[i] = 0; lcur[i] = 0; }
    __syncthreads();

    int base = blockIdx.x * EPB;
    unsigned int regR[EPB / 256];
    short regB[EPB / 256];
    #pragma unroll
    for (int j = 0; j < EPB / 1024; j++) {
        int i = base + (j * 256 + t) * 4;   // 4-aligned; never straddles NE
        if (i < TWO_NE) {
            int g = i >= NE;
            int e = i - g * NE;
            const int* eix = g ? en : ep;
            int4 s4 = *(const int4*)(eix + e);
            int4 d4 = *(const int4*)(eix + NE + e);
            int off = g * N_NODES;
            int ss[4] = {s4.x, s4.y, s4.z, s4.w};
            int dd[4] = {d4.x, d4.y, d4.z, d4.w};
            #pragma unroll
            for (int k = 0; k < 4; k++) {
                int src = ss[k] + off;
                int dst = dd[k] + off;
                int b = dst >> 8;
                regB[j * 4 + k] = (short)b;
                regR[j * 4 + k] = ((unsigned int)(dst & 255) << 18) | (unsigned int)src;
                atomicAdd(&hist[b], 1);
            }
        } else {
            #pragma unroll
            for (int k = 0; k < 4; k++) regB[j * 4 + k] = -1;
        }
    }
    __syncthreads();

    // claim contiguous global space per nonempty bucket (1 global atomic each)
    for (int b = t; b < NBUCK; b += 256) {
        int c = hist[b];
        claim[b] = c ? atomicAdd(&gcur[b], c) : 0;
    }
    __syncthreads();

    // direct placement: rank within (block,bucket) via LDS atomic
    #pragma unroll
    for (int j = 0; j < EPB / 256; j++) {
        int b = regB[j];
        if (b >= 0) {
            int r = atomicAdd(&lcur[b], 1);
            buf[claim[b] + r] = regR[j];
        }
    }
}

// ---------------------------------------------------------------------------
// Kernel 2 (pass B): per bucket, in-place: stage bucket in LDS, build
// 16-PADDED per-row lists (pads = ZROW), row {start,deg} + inv.
// ---------------------------------------------------------------------------
__global__ __launch_bounds__(256) void csr_build_kernel(
    const int* __restrict__ gcur,
    unsigned int* __restrict__ buf,     // bucketed in, padded slots out (in-place)
    int2* __restrict__ rs2,
    float* __restrict__ inv)
{
    __shared__ unsigned int recs[CAP_STG];
    __shared__ int hist[256];
    __shared__ int scn[256];
    __shared__ int lcur[256];

    int t = threadIdx.x;
    int b = blockIdx.x;
    int gbase = b * CAP_PAD;
    int cnt = gcur[b] - gbase;
    if (cnt > CAP_STG) cnt = CAP_STG;   // statistically never

    hist[t] = 0;
    __syncthreads();
    for (int i = t; i < cnt; i += 256) {
        unsigned int r = buf[gbase + i];
        recs[i] = r;
        atomicAdd(&hist[r >> 18], 1);
    }
    __syncthreads();
    int v  = hist[t];
    int pv = (v + 15) & ~15;            // padded row length
    scn[t] = pv;
    __syncthreads();
    for (int off = 1; off < 256; off <<= 1) {
        int u = (t >= off) ? scn[t - off] : 0;
        __syncthreads();
        scn[t] += u;
        __syncthreads();
    }
    int excl = scn[t] - pv;             // padded exclusive prefix
    int row = (b << 8) + t;
    if (row < TWO_N) {
        rs2[row] = make_int2(gbase + excl, v);
        inv[row] = rsqrtf((float)v + 1.0f);
    }
    lcur[t] = excl;
    __syncthreads();
    for (int i = t; i < cnt; i += 256) {
        unsigned int r = recs[i];
        int rk = atomicAdd(&lcur[r >> 18], 1);
        buf[gbase + rk] = r & 0x3FFFFu;
    }
    // pad this thread's row to a multiple of 16 with the zero-row index
    for (int i = v; i < pv; i++) buf[gbase + excl + i] = ZROW;
}

// ---------------------------------------------------------------------------
// Kernel 3: LayerNorm + two HxH GEMVs, outputs pre-scaled by inv[row],
// packed to bf16 pairs: xh[row][fp] = {feat 2fp, feat 2fp+1}, row' in [0,2N).
// ---------------------------------------------------------------------------
__global__ __launch_bounds__(256) void ln_xw_kernel(
    const float* __restrict__ h,
    const float* __restrict__ gamma,
    const float* __restrict__ beta,
    const float* __restrict__ Wp,
    const float* __restrict__ Wn,
    const float* __restrict__ inv,
    __hip_bfloat162* __restrict__ xh)
{
    __shared__ float sWp[H * H];
    __shared__ float sWn[H * H];
    __shared__ float sHn[8][H];

    int tid = threadIdx.x;
    for (int i = tid; i < H * H; i += 256) { sWp[i] = Wp[i]; sWn[i] = Wn[i]; }

    int lane = tid & 31;
    int r    = tid >> 5;
    int row  = blockIdx.x * 8 + r;

    float x = h[row * H + lane];
    float s = x;
    #pragma unroll
    for (int m = 16; m >= 1; m >>= 1) s += __shfl_xor(s, m);
    float mu = s * (1.0f / 32.0f);
    float d  = x - mu;
    float v  = d * d;
    #pragma unroll
    for (int m = 16; m >= 1; m >>= 1) v += __shfl_xor(v, m);
    float rstd = rsqrtf(v * (1.0f / 32.0f) + LN_EPS);
    float hn   = d * rstd * gamma[lane] + beta[lane];

    sHn[r][lane] = hn;
    __syncthreads();

    float accp = 0.f, accn = 0.f;
    #pragma unroll
    for (int k = 0; k < H; k++) {
        float hk = sHn[r][k];
        accp += hk * sWp[k * H + lane];
        accn += hk * sWn[k * H + lane];
    }
    float vp = accp * inv[row];
    float vn = accn * inv[N_NODES + row];

    // pack feature pairs: even lane stores {self, odd-partner}
    float vp_nb = __shfl_xor(vp, 1);
    float vn_nb = __shfl_xor(vn, 1);
    if ((lane & 1) == 0) {
        __hip_bfloat162 pv, nv;
        pv.x = __float2bfloat16(vp); pv.y = __float2bfloat16(vp_nb);
        nv.x = __float2bfloat16(vn); nv.y = __float2bfloat16(vn_nb);
        int fp = lane >> 1;
        xh[row * 16 + fp]               = pv;
        xh[(N_NODES + row) * 16 + fp]   = nv;
    }
}

// ---------------------------------------------------------------------------
// Kernel 4: atomic-free gather, wave per row, pos+neg interleaved, TAIL-FREE
// (lists padded to x16 with ZROW). Then bias + psi GEMV + tanh + damping.
// ---------------------------------------------------------------------------
__global__ __launch_bounds__(256) void gather_final_kernel(
    const float* __restrict__ h,
    const float* __restrict__ gamma,
    const float* __restrict__ beta,
    const __hip_bfloat162* __restrict__ xh,
    const int* __restrict__ slot,
    const float* __restrict__ inv,
    const int2* __restrict__ rs2,
    const float* __restrict__ bp,
    const float* __restrict__ bn,
    const float* __restrict__ Wpsi,
    float* __restrict__ out)
{
    __shared__ float sW[2 * H * H];
    __shared__ float sP[4][H];
    __shared__ float sM[4][H];

    int tid = threadIdx.x;
    for (int i = tid; i < 2 * H * H; i += 256) sW[i] = Wpsi[i];

    int wave = tid >> 6;
    int lane = tid & 63;
    int grp  = lane >> 4;        // edge group 0..3
    int fp   = lane & 15;        // feature pair 0..15
    int row  = blockIdx.x * 4 + wave;
    int rn   = N_NODES + row;

    int2 RP = rs2[row];          // {start, deg}
    int2 RN = rs2[rn];
    int np = (RP.y + 15) >> 4;   // full 16-edge chunks (padded)
    int nn = (RN.y + 15) >> 4;
    int nmax = np > nn ? np : nn;

    float ap0 = 0.f, ap1 = 0.f, an0 = 0.f, an1 = 0.f;
    int slp = 0, sln = 0;

    for (int c = 0; c < nmax; c++) {
        bool dop = c < np, don = c < nn;
        if ((c & 3) == 0) {
            if (dop) slp = slot[RP.x + (c << 4) + lane];
            if (don) sln = slot[RN.x + (c << 4) + lane];
        }
        int sb = ((c & 3) << 4) + (grp << 2);
        __hip_bfloat162 vp0, vp1, vp2, vp3, vn0, vn1, vn2, vn3;
        if (dop) {
            int s0 = __shfl(slp, sb + 0, 64), s1 = __shfl(slp, sb + 1, 64);
            int s2 = __shfl(slp, sb + 2, 64), s3 = __shfl(slp, sb + 3, 64);
            vp0 = xh[s0 * 16 + fp]; vp1 = xh[s1 * 16 + fp];
            vp2 = xh[s2 * 16 + fp]; vp3 = xh[s3 * 16 + fp];
        }
        if (don) {
            int s0 = __shfl(sln, sb + 0, 64), s1 = __shfl(sln, sb + 1, 64);
            int s2 = __shfl(sln, sb + 2, 64), s3 = __shfl(sln, sb + 3, 64);
            vn0 = xh[s0 * 16 + fp]; vn1 = xh[s1 * 16 + fp];
            vn2 = xh[s2 * 16 + fp]; vn3 = xh[s3 * 16 + fp];
        }
        if (dop) {
            ap0 += __bfloat162float(vp0.x) + __bfloat162float(vp1.x)
                 + __bfloat162float(vp2.x) + __bfloat162float(vp3.x);
            ap1 += __bfloat162float(vp0.y) + __bfloat162float(vp1.y)
                 + __bfloat162float(vp2.y) + __bfloat162float(vp3.y);
        }
        if (don) {
            an0 += __bfloat162float(vn0.x) + __bfloat162float(vn1.x)
                 + __bfloat162float(vn2.x) + __bfloat162float(vn3.x);
            an1 += __bfloat162float(vn0.y) + __bfloat162float(vn1.y)
                 + __bfloat162float(vn2.y) + __bfloat162float(vn3.y);
        }
    }

    // reduce across the 4 edge groups
    ap0 += __shfl_xor(ap0, 16); ap0 += __shfl_xor(ap0, 32);
    ap1 += __shfl_xor(ap1, 16); ap1 += __shfl_xor(ap1, 32);
    an0 += __shfl_xor(an0, 16); an0 += __shfl_xor(an0, 32);
    an1 += __shfl_xor(an1, 16); an1 += __shfl_xor(an1, 32);

    // self loops (already inv-scaled) + outer inv + bias
    __hip_bfloat162 svp = xh[row * 16 + fp];
    __hip_bfloat162 svn = xh[rn * 16 + fp];
    float ivp = inv[row], ivn = inv[rn];
    float hp0 = ivp * (ap0 + __bfloat162float(svp.x)) + bp[2 * fp];
    float hp1 = ivp * (ap1 + __bfloat162float(svp.y)) + bp[2 * fp + 1];
    float hm0 = ivn * (an0 + __bfloat162float(svn.x)) + bn[2 * fp];
    float hm1 = ivn * (an1 + __bfloat162float(svn.y)) + bn[2 * fp + 1];

    if (grp == 0) {
        sP[wave][2 * fp]     = hp0;
        sP[wave][2 * fp + 1] = hp1;
        sM[wave][2 * fp]     = hm0;
        sM[wave][2 * fp + 1] = hm1;
    }
    __syncthreads();

    // ---- epilogue: LN recompute + psi + tanh + damping + clip (128 thr) ----
    if (tid < 128) {
        int r     = tid >> 5;
        int lane2 = tid & 31;
        int row2  = blockIdx.x * 4 + r;

        float x = h[row2 * H + lane2];
        float s = x;
        #pragma unroll
        for (int m = 16; m >= 1; m >>= 1) s += __shfl_xor(s, m);
        float mu = s * (1.0f / 32.0f);
        float d  = x - mu;
        float v  = d * d;
        #pragma unroll
        for (int m = 16; m >= 1; m >>= 1) v += __shfl_xor(v, m);
        float rstd = rsqrtf(v * (1.0f / 32.0f) + LN_EPS);
        float hn   = d * rstd * gamma[lane2] + beta[lane2];

        float acc = 0.f;
        #pragma unroll
        for (int k = 0; k < H; k++) {
            acc += sP[r][k] * sW[k * H + lane2];
            acc += sM[r][k] * sW[(H + k) * H + lane2];
        }

        float delta = tanhf(acc) - DAMPING * hn;
        delta = fminf(fmaxf(delta, -50.f), 50.f);
        out[row2 * H + lane2] = delta;
    }
}

// ---------------------------------------------------------------------------
extern "C" void kernel_launch(void* const* d_in, const int* in_sizes, int n_in,
                              void* d_out, int out_size, void* d_ws, size_t ws_size,
                              hipStream_t stream)
{
    const float* h      = (const float*)d_in[1];
    const int*   ep     = (const int*)  d_in[2];   // (2, E)
    const int*   en     = (const int*)  d_in[3];
    const float* gamma  = (const float*)d_in[4];
    const float* beta   = (const float*)d_in[5];
    const float* Wp     = (const float*)d_in[6];
    const float* bp     = (const float*)d_in[7];
    const float* Wn     = (const float*)d_in[8];
    const float* bn     = (const float*)d_in[9];
    const float* Wpsi   = (const float*)d_in[10];
    float* out = (float*)d_out;

    // workspace layout (52.0 MB total):
    unsigned int* buf = (unsigned int*)d_ws;                     // NBUCK*CAP_PAD u32 (36.8 MB)
    __hip_bfloat162* xh = (__hip_bfloat162*)(buf + (size_t)NBUCK * CAP_PAD); // (2N+1)*16 (12.8 MB)
    int2*  rs2  = (int2*)(xh + (size_t)(TWO_N + 1) * 16);        // 2N int2 (1.6 MB)
    float* inv  = (float*)(rs2 + TWO_N);                         // 2N f32 (0.8 MB)
    int*   gcur = (int*)(inv + TWO_N);                           // NBUCK

    init_kernel<<<4, 256, 0, stream>>>(gcur, (unsigned int*)(xh + (size_t)ZROW * 16));

    bucket_scatter_kernel<<<NBLK_A, 256, 0, stream>>>(ep, en, gcur, buf);

    csr_build_kernel<<<NBUCK, 256, 0, stream>>>(gcur, buf, rs2, inv);

    ln_xw_kernel<<<N_NODES / 8, 256, 0, stream>>>(h, gamma, beta, Wp, Wn, inv, xh);

    gather_final_kernel<<<N_NODES / 4, 256, 0, stream>>>(
        h, gamma, beta, xh, (const int*)buf, inv, rs2, bp, bn, Wpsi, out);
}

// Round 8
// 315.531 us; speedup vs baseline: 1.0432x; 1.0432x over previous
//
#include <hip/hip_runtime.h>
#include <hip/hip_bf16.h>
#include <math.h>

#define N_NODES 100000
#define NE      3200000
#define TWO_NE  (2 * NE)
#define TWO_N   (2 * N_NODES)
#define H       32
#define DAMPING 0.1f
#define LN_EPS  1e-5f

#define NBUCK    782           // ceil(2N / 256) coarse dst buckets (256 rows each)
#define CAP_PAD  11776         // bucket region incl. 16-pads (mean padded 10112, +14 sigma)
#define CAP_STG  8960          // LDS staging cap (raw counts; mean 8192 + 8.5 sigma)
#define EPB      8192          // edges per scatter block
#define NBLK_A   ((TWO_NE + EPB - 1) / EPB)   // 782
#define ZROW     TWO_N         // dedicated all-zero xh row used for padding
#define GSTRIDE  16            // gcur padding: one cursor per 64B line (anti false-sharing)

// ---------------------------------------------------------------------------
// Kernel 0: init per-bucket cursors (line-padded) + zero the xh pad row.
// ---------------------------------------------------------------------------
__global__ __launch_bounds__(256) void init_kernel(
    int* __restrict__ gcur, unsigned int* __restrict__ xhz)
{
    int i = blockIdx.x * 256 + threadIdx.x;
    if (i < NBUCK) gcur[i * GSTRIDE] = i * CAP_PAD;
    if (i < 16)    xhz[i] = 0;             // xh row ZROW (16 x bf16x2 = 64 B)
}

// ---------------------------------------------------------------------------
// Kernel 1 (pass A): LDS counting-sort edges by coarse bucket; one global
// claim per (block,bucket) on LINE-PADDED cursors; coalesced run writes.
// rec = (dst' & 255) << 18 | src'   (src' < 2^18)
// ---------------------------------------------------------------------------
__global__ __launch_bounds__(256) void bucket_scatter_kernel(
    const int* __restrict__ ep, const int* __restrict__ en,
    int* __restrict__ gcur, unsigned int* __restrict__ buf)
{
    __shared__ int hist[NBUCK];
    __shared__ int lexcl[NBUCK];
    __shared__ int lcur[NBUCK];
    __shared__ int claim[NBUCK];
    __shared__ int partial[256];
    __shared__ unsigned int srec[EPB];
    __shared__ unsigned short sbid[EPB];

    int t = threadIdx.x;
    for (int i = t; i < NBUCK; i += 256) { hist[i] = 0; lcur[i] = 0; }
    __syncthreads();

    int base = blockIdx.x * EPB;
    unsigned int regR[EPB / 256];
    short regB[EPB / 256];
    #pragma unroll
    for (int j = 0; j < EPB / 1024; j++) {
        int i = base + (j * 256 + t) * 4;   // 4-aligned; never straddles NE
        if (i < TWO_NE) {
            int g = i >= NE;
            int e = i - g * NE;
            const int* eix = g ? en : ep;
            int4 s4 = *(const int4*)(eix + e);
            int4 d4 = *(const int4*)(eix + NE + e);
            int off = g * N_NODES;
            int ss[4] = {s4.x, s4.y, s4.z, s4.w};
            int dd[4] = {d4.x, d4.y, d4.z, d4.w};
            #pragma unroll
            for (int k = 0; k < 4; k++) {
                int src = ss[k] + off;
                int dst = dd[k] + off;
                int b = dst >> 8;
                regB[j * 4 + k] = (short)b;
                regR[j * 4 + k] = ((unsigned int)(dst & 255) << 18) | (unsigned int)src;
                atomicAdd(&hist[b], 1);
            }
        } else {
            #pragma unroll
            for (int k = 0; k < 4; k++) regB[j * 4 + k] = -1;
        }
    }
    __syncthreads();

    // exclusive scan over hist[0..NBUCK): 4 cells/thread + Hillis over partials
    int h0[4]; int ssum = 0;
    #pragma unroll
    for (int k = 0; k < 4; k++) {
        int idx = t * 4 + k;
        h0[k] = (idx < NBUCK) ? hist[idx] : 0;
        ssum += h0[k];
    }
    partial[t] = ssum;
    __syncthreads();
    for (int off = 1; off < 256; off <<= 1) {
        int u = (t >= off) ? partial[t - off] : 0;
        __syncthreads();
        partial[t] += u;
        __syncthreads();
    }
    int run = partial[t] - ssum;
    #pragma unroll
    for (int k = 0; k < 4; k++) {
        int idx = t * 4 + k;
        if (idx < NBUCK) lexcl[idx] = run;
        run += h0[k];
    }
    __syncthreads();

    // claim contiguous global space per nonempty bucket — each cursor on its
    // own cache line, so claims across blocks queue per-bucket, not per-line.
    for (int b = t; b < NBUCK; b += 256) {
        int c = hist[b];
        claim[b] = c ? atomicAdd(&gcur[b * GSTRIDE], c) : 0;
    }
    __syncthreads();

    // place edges sorted-by-bucket into LDS
    #pragma unroll
    for (int j = 0; j < EPB / 256; j++) {
        int b = regB[j];
        if (b >= 0) {
            int r = atomicAdd(&lcur[b], 1);
            int s = lexcl[b] + r;
            srec[s] = regR[j];
            sbid[s] = (unsigned short)b;
        }
    }
    __syncthreads();

    // coalesced-run writes: consecutive s within a bucket -> consecutive global
    int cnt = partial[255];
    for (int s = t; s < cnt; s += 256) {
        int b = sbid[s];
        buf[claim[b] + (s - lexcl[b])] = srec[s];
    }
}

// ---------------------------------------------------------------------------
// Kernel 2 (pass B): per bucket, in-place: stage bucket in LDS, build
// 16-PADDED per-row lists (pads = ZROW), row {start,deg} + inv.
// ---------------------------------------------------------------------------
__global__ __launch_bounds__(256) void csr_build_kernel(
    const int* __restrict__ gcur,
    unsigned int* __restrict__ buf,     // bucketed in, padded slots out (in-place)
    int2* __restrict__ rs2,
    float* __restrict__ inv)
{
    __shared__ unsigned int recs[CAP_STG];
    __shared__ int hist[256];
    __shared__ int scn[256];
    __shared__ int lcur[256];

    int t = threadIdx.x;
    int b = blockIdx.x;
    int gbase = b * CAP_PAD;
    int cnt = gcur[b * GSTRIDE] - gbase;
    if (cnt > CAP_STG) cnt = CAP_STG;   // statistically never

    hist[t] = 0;
    __syncthreads();
    for (int i = t; i < cnt; i += 256) {
        unsigned int r = buf[gbase + i];
        recs[i] = r;
        atomicAdd(&hist[r >> 18], 1);
    }
    __syncthreads();
    int v  = hist[t];
    int pv = (v + 15) & ~15;            // padded row length
    scn[t] = pv;
    __syncthreads();
    for (int off = 1; off < 256; off <<= 1) {
        int u = (t >= off) ? scn[t - off] : 0;
        __syncthreads();
        scn[t] += u;
        __syncthreads();
    }
    int excl = scn[t] - pv;             // padded exclusive prefix
    int row = (b << 8) + t;
    if (row < TWO_N) {
        rs2[row] = make_int2(gbase + excl, v);
        inv[row] = rsqrtf((float)v + 1.0f);
    }
    lcur[t] = excl;
    __syncthreads();
    for (int i = t; i < cnt; i += 256) {
        unsigned int r = recs[i];
        int rk = atomicAdd(&lcur[r >> 18], 1);
        buf[gbase + rk] = r & 0x3FFFFu;
    }
    // pad this thread's row to a multiple of 16 with the zero-row index
    for (int i = v; i < pv; i++) buf[gbase + excl + i] = ZROW;
}

// ---------------------------------------------------------------------------
// Kernel 3: LayerNorm + two HxH GEMVs, outputs pre-scaled by inv[row],
// packed to bf16 pairs: xh[row][fp] = {feat 2fp, feat 2fp+1}, row' in [0,2N).
// ---------------------------------------------------------------------------
__global__ __launch_bounds__(256) void ln_xw_kernel(
    const float* __restrict__ h,
    const float* __restrict__ gamma,
    const float* __restrict__ beta,
    const float* __restrict__ Wp,
    const float* __restrict__ Wn,
    const float* __restrict__ inv,
    __hip_bfloat162* __restrict__ xh)
{
    __shared__ float sWp[H * H];
    __shared__ float sWn[H * H];
    __shared__ float sHn[8][H];

    int tid = threadIdx.x;
    for (int i = tid; i < H * H; i += 256) { sWp[i] = Wp[i]; sWn[i] = Wn[i]; }

    int lane = tid & 31;
    int r    = tid >> 5;
    int row  = blockIdx.x * 8 + r;

    float x = h[row * H + lane];
    float s = x;
    #pragma unroll
    for (int m = 16; m >= 1; m >>= 1) s += __shfl_xor(s, m);
    float mu = s * (1.0f / 32.0f);
    float d  = x - mu;
    float v  = d * d;
    #pragma unroll
    for (int m = 16; m >= 1; m >>= 1) v += __shfl_xor(v, m);
    float rstd = rsqrtf(v * (1.0f / 32.0f) + LN_EPS);
    float hn   = d * rstd * gamma[lane] + beta[lane];

    sHn[r][lane] = hn;
    __syncthreads();

    float accp = 0.f, accn = 0.f;
    #pragma unroll
    for (int k = 0; k < H; k++) {
        float hk = sHn[r][k];
        accp += hk * sWp[k * H + lane];
        accn += hk * sWn[k * H + lane];
    }
    float vp = accp * inv[row];
    float vn = accn * inv[N_NODES + row];

    // pack feature pairs: even lane stores {self, odd-partner}
    float vp_nb = __shfl_xor(vp, 1);
    float vn_nb = __shfl_xor(vn, 1);
    if ((lane & 1) == 0) {
        __hip_bfloat162 pv, nv;
        pv.x = __float2bfloat16(vp); pv.y = __float2bfloat16(vp_nb);
        nv.x = __float2bfloat16(vn); nv.y = __float2bfloat16(vn_nb);
        int fp = lane >> 1;
        xh[row * 16 + fp]               = pv;
        xh[(N_NODES + row) * 16 + fp]   = nv;
    }
}

// ---------------------------------------------------------------------------
// Kernel 4: atomic-free gather, wave per row, pos+neg interleaved, TAIL-FREE
// (lists padded to x16 with ZROW). Then bias + psi GEMV + tanh + damping.
// ---------------------------------------------------------------------------
__global__ __launch_bounds__(256) void gather_final_kernel(
    const float* __restrict__ h,
    const float* __restrict__ gamma,
    const float* __restrict__ beta,
    const __hip_bfloat162* __restrict__ xh,
    const int* __restrict__ slot,
    const float* __restrict__ inv,
    const int2* __restrict__ rs2,
    const float* __restrict__ bp,
    const float* __restrict__ bn,
    const float* __restrict__ Wpsi,
    float* __restrict__ out)
{
    __shared__ float sW[2 * H * H];
    __shared__ float sP[4][H];
    __shared__ float sM[4][H];

    int tid = threadIdx.x;
    for (int i = tid; i < 2 * H * H; i += 256) sW[i] = Wpsi[i];

    int wave = tid >> 6;
    int lane = tid & 63;
    int grp  = lane >> 4;        // edge group 0..3
    int fp   = lane & 15;        // feature pair 0..15
    int row  = blockIdx.x * 4 + wave;
    int rn   = N_NODES + row;

    int2 RP = rs2[row];          // {start, deg}
    int2 RN = rs2[rn];
    int np = (RP.y + 15) >> 4;   // full 16-edge chunks (padded)
    int nn = (RN.y + 15) >> 4;
    int nmax = np > nn ? np : nn;

    float ap0 = 0.f, ap1 = 0.f, an0 = 0.f, an1 = 0.f;
    int slp = 0, sln = 0;

    for (int c = 0; c < nmax; c++) {
        bool dop = c < np, don = c < nn;
        if ((c & 3) == 0) {
            if (dop) slp = slot[RP.x + (c << 4) + lane];
            if (don) sln = slot[RN.x + (c << 4) + lane];
        }
        int sb = ((c & 3) << 4) + (grp << 2);
        __hip_bfloat162 vp0, vp1, vp2, vp3, vn0, vn1, vn2, vn3;
        if (dop) {
            int s0 = __shfl(slp, sb + 0, 64), s1 = __shfl(slp, sb + 1, 64);
            int s2 = __shfl(slp, sb + 2, 64), s3 = __shfl(slp, sb + 3, 64);
            vp0 = xh[s0 * 16 + fp]; vp1 = xh[s1 * 16 + fp];
            vp2 = xh[s2 * 16 + fp]; vp3 = xh[s3 * 16 + fp];
        }
        if (don) {
            int s0 = __shfl(sln, sb + 0, 64), s1 = __shfl(sln, sb + 1, 64);
            int s2 = __shfl(sln, sb + 2, 64), s3 = __shfl(sln, sb + 3, 64);
            vn0 = xh[s0 * 16 + fp]; vn1 = xh[s1 * 16 + fp];
            vn2 = xh[s2 * 16 + fp]; vn3 = xh[s3 * 16 + fp];
        }
        if (dop) {
            ap0 += __bfloat162float(vp0.x) + __bfloat162float(vp1.x)
                 + __bfloat162float(vp2.x) + __bfloat162float(vp3.x);
            ap1 += __bfloat162float(vp0.y) + __bfloat162float(vp1.y)
                 + __bfloat162float(vp2.y) + __bfloat162float(vp3.y);
        }
        if (don) {
            an0 += __bfloat162float(vn0.x) + __bfloat162float(vn1.x)
                 + __bfloat162float(vn2.x) + __bfloat162float(vn3.x);
            an1 += __bfloat162float(vn0.y) + __bfloat162float(vn1.y)
                 + __bfloat162float(vn2.y) + __bfloat162float(vn3.y);
        }
    }

    // reduce across the 4 edge groups
    ap0 += __shfl_xor(ap0, 16); ap0 += __shfl_xor(ap0, 32);
    ap1 += __shfl_xor(ap1, 16); ap1 += __shfl_xor(ap1, 32);
    an0 += __shfl_xor(an0, 16); an0 += __shfl_xor(an0, 32);
    an1 += __shfl_xor(an1, 16); an1 += __shfl_xor(an1, 32);

    // self loops (already inv-scaled) + outer inv + bias
    __hip_bfloat162 svp = xh[row * 16 + fp];
    __hip_bfloat162 svn = xh[rn * 16 + fp];
    float ivp = inv[row], ivn = inv[rn];
    float hp0 = ivp * (ap0 + __bfloat162float(svp.x)) + bp[2 * fp];
    float hp1 = ivp * (ap1 + __bfloat162float(svp.y)) + bp[2 * fp + 1];
    float hm0 = ivn * (an0 + __bfloat162float(svn.x)) + bn[2 * fp];
    float hm1 = ivn * (an1 + __bfloat162float(svn.y)) + bn[2 * fp + 1];

    if (grp == 0) {
        sP[wave][2 * fp]     = hp0;
        sP[wave][2 * fp + 1] = hp1;
        sM[wave][2 * fp]     = hm0;
        sM[wave][2 * fp + 1] = hm1;
    }
    __syncthreads();

    // ---- epilogue: LN recompute + psi + tanh + damping + clip (128 thr) ----
    if (tid < 128) {
        int r     = tid >> 5;
        int lane2 = tid & 31;
        int row2  = blockIdx.x * 4 + r;

        float x = h[row2 * H + lane2];
        float s = x;
        #pragma unroll
        for (int m = 16; m >= 1; m >>= 1) s += __shfl_xor(s, m);
        float mu = s * (1.0f / 32.0f);
        float d  = x - mu;
        float v  = d * d;
        #pragma unroll
        for (int m = 16; m >= 1; m >>= 1) v += __shfl_xor(v, m);
        float rstd = rsqrtf(v * (1.0f / 32.0f) + LN_EPS);
        float hn   = d * rstd * gamma[lane2] + beta[lane2];

        float acc = 0.f;
        #pragma unroll
        for (int k = 0; k < H; k++) {
            acc += sP[r][k] * sW[k * H + lane2];
            acc += sM[r][k] * sW[(H + k) * H + lane2];
        }

        float delta = tanhf(acc) - DAMPING * hn;
        delta = fminf(fmaxf(delta, -50.f), 50.f);
        out[row2 * H + lane2] = delta;
    }
}

// ---------------------------------------------------------------------------
extern "C" void kernel_launch(void* const* d_in, const int* in_sizes, int n_in,
                              void* d_out, int out_size, void* d_ws, size_t ws_size,
                              hipStream_t stream)
{
    const float* h      = (const float*)d_in[1];
    const int*   ep     = (const int*)  d_in[2];   // (2, E)
    const int*   en     = (const int*)  d_in[3];
    const float* gamma  = (const float*)d_in[4];
    const float* beta   = (const float*)d_in[5];
    const float* Wp     = (const float*)d_in[6];
    const float* bp     = (const float*)d_in[7];
    const float* Wn     = (const float*)d_in[8];
    const float* bn     = (const float*)d_in[9];
    const float* Wpsi   = (const float*)d_in[10];
    float* out = (float*)d_out;

    // workspace layout (52.1 MB total):
    unsigned int* buf = (unsigned int*)d_ws;                     // NBUCK*CAP_PAD u32 (36.8 MB)
    __hip_bfloat162* xh = (__hip_bfloat162*)(buf + (size_t)NBUCK * CAP_PAD); // (2N+1)*16 (12.8 MB)
    int2*  rs2  = (int2*)(xh + (size_t)(TWO_N + 1) * 16);        // 2N int2 (1.6 MB)
    float* inv  = (float*)(rs2 + TWO_N);                         // 2N f32 (0.8 MB)
    int*   gcur = (int*)(inv + TWO_N);                           // NBUCK*16 (50 KB, line-padded)

    init_kernel<<<4, 256, 0, stream>>>(gcur, (unsigned int*)(xh + (size_t)ZROW * 16));

    bucket_scatter_kernel<<<NBLK_A, 256, 0, stream>>>(ep, en, gcur, buf);

    csr_build_kernel<<<NBUCK, 256, 0, stream>>>(gcur, buf, rs2, inv);

    ln_xw_kernel<<<N_NODES / 8, 256, 0, stream>>>(h, gamma, beta, Wp, Wn, inv, xh);

    gather_final_kernel<<<N_NODES / 4, 256, 0, stream>>>(
        h, gamma, beta, xh, (const int*)buf, inv, rs2, bp, bn, Wpsi, out);
}